// Round 3
// baseline (119.016 us; speedup 1.0000x reference)
//
#include <hip/hip_runtime.h>
#include <hip/hip_bf16.h>

// GuidedAttentionLoss: out = sum(w * p over valid) / count(valid)
//   w = 1 - exp(-((s/il - t/ol)^2) / (2*sigma^2)), valid = (t<ol)&(s<il)
// Shapes fixed by reference: B=32, T=2048, S=512.
// Single fused kernel: per-block partial + last-block-done final reduction.

#define GA_T 2048
#define GA_S 512
#define GA_INV2S2 (1.0f / (2.0f * 0.4f * 0.4f))

#define BLOCK 256
#define ROWS_PER_BLOCK 16                 // rows of T per block
#define TILES_X (GA_T / ROWS_PER_BLOCK)   // 128
#define NPART (TILES_X * 32)              // 4096 blocks

__global__ __launch_bounds__(BLOCK) void ga_fused_kernel(
    const int* __restrict__ slen, const int* __restrict__ tlen,
    const float* __restrict__ p, float* __restrict__ partial,
    unsigned int* __restrict__ counter, float* __restrict__ out, int B) {
  const int b = blockIdx.y;
  const int t0 = blockIdx.x * ROWS_PER_BLOCK;
  const int bi = b * gridDim.x + blockIdx.x;
  const int ol = tlen[b];

  float acc = 0.0f;

  if (t0 < ol) {
    const int il = slen[b];
    const float inv_il = 1.0f / (float)il;
    const float inv_ol = 1.0f / (float)ol;

    const int r = threadIdx.x >> 7;    // 0..1 (uniform per wave)
    const int sv = threadIdx.x & 127;  // column slot
    const int s0 = sv << 2;

    if (s0 < il) {
      const float ys0 = (float)(s0 + 0) * inv_il;
      const float ys1 = (float)(s0 + 1) * inv_il;
      const float ys2 = (float)(s0 + 2) * inv_il;
      const float ys3 = (float)(s0 + 3) * inv_il;
      const float m1 = (s0 + 1 < il) ? 1.0f : 0.0f;
      const float m2 = (s0 + 2 < il) ? 1.0f : 0.0f;
      const float m3 = (s0 + 3 < il) ? 1.0f : 0.0f;

      const float* base = p + ((size_t)(b * GA_T + t0 + r) * GA_S + s0);

#pragma unroll
      for (int rr = 0; rr < ROWS_PER_BLOCK; rr += 2) {
        const int t = t0 + rr + r;
        if (t >= ol) break;  // wave-uniform (r uniform per wave)
        const float4 pv = *reinterpret_cast<const float4*>(base + rr * GA_S);
        const float xo = (float)t * inv_ol;
        float d0 = ys0 - xo, d1 = ys1 - xo, d2 = ys2 - xo, d3 = ys3 - xo;
        float e0 = __expf(-(d0 * d0) * GA_INV2S2);
        float e1 = __expf(-(d1 * d1) * GA_INV2S2);
        float e2 = __expf(-(d2 * d2) * GA_INV2S2);
        float e3 = __expf(-(d3 * d3) * GA_INV2S2);
        // w*p = p - p*e  (2 FMAs/elem), masks folded into p
        float p0 = pv.x, p1 = m1 * pv.y, p2 = m2 * pv.z, p3 = m3 * pv.w;
        acc += p0 - p0 * e0;
        acc += p1 - p1 * e1;
        acc += p2 - p2 * e2;
        acc += p3 - p3 * e3;
      }
    }
  }

  // ---- block reduction (deterministic fixed tree) ----
  for (int off = 32; off > 0; off >>= 1)
    acc += __shfl_down(acc, off, 64);

  __shared__ float wsum[BLOCK / 64];
  __shared__ int sh_last;
  const int lane = threadIdx.x & 63;
  const int wid = threadIdx.x >> 6;
  if (lane == 0) wsum[wid] = acc;
  __syncthreads();

  if (threadIdx.x == 0) {
    float tot = (wsum[0] + wsum[1]) + (wsum[2] + wsum[3]);
    // agent-scope store so it's visible across XCDs at the coherence point
    __hip_atomic_store(&partial[bi], tot, __ATOMIC_RELAXED,
                       __HIP_MEMORY_SCOPE_AGENT);
    unsigned int old = __hip_atomic_fetch_add(counter, 1u, __ATOMIC_ACQ_REL,
                                              __HIP_MEMORY_SCOPE_AGENT);
    sh_last = (old == (unsigned int)(NPART - 1)) ? 1 : 0;
  }
  __syncthreads();
  if (!sh_last) return;

  // ---- last block: reduce all partials (deterministic fixed order) ----
  double a0 = 0.0, a1 = 0.0;
#pragma unroll
  for (int k = 0; k < NPART / (2 * BLOCK); ++k) {
    int i0 = k * 2 * BLOCK + threadIdx.x;
    a0 += (double)__hip_atomic_load(&partial[i0], __ATOMIC_RELAXED,
                                    __HIP_MEMORY_SCOPE_AGENT);
    a1 += (double)__hip_atomic_load(&partial[i0 + BLOCK], __ATOMIC_RELAXED,
                                    __HIP_MEMORY_SCOPE_AGENT);
  }
  double s = a0 + a1;

  __shared__ double sh[BLOCK];
  sh[threadIdx.x] = s;
  __syncthreads();
  for (int off = BLOCK / 2; off > 0; off >>= 1) {
    if (threadIdx.x < off) sh[threadIdx.x] += sh[threadIdx.x + off];
    __syncthreads();
  }
  if (threadIdx.x == 0) {
    double den = 0.0;
    for (int bb = 0; bb < B; ++bb)
      den += (double)slen[bb] * (double)tlen[bb];
    out[0] = (float)(sh[0] / den);
  }
}

extern "C" void kernel_launch(void* const* d_in, const int* in_sizes, int n_in,
                              void* d_out, int out_size, void* d_ws, size_t ws_size,
                              hipStream_t stream) {
  const int* slen = (const int*)d_in[0];
  const int* tlen = (const int*)d_in[1];
  const float* p = (const float*)d_in[2];
  float* out = (float*)d_out;

  float* partial = (float*)d_ws;                      // NPART floats = 16 KB
  unsigned int* counter = (unsigned int*)((char*)d_ws + NPART * sizeof(float));

  const int B = in_sizes[0];  // 32

  // zero the arrival counter every call (ws is poisoned once, not re-poisoned;
  // kernel leaves counter==NPART, so reset is required each launch)
  hipMemsetAsync(counter, 0, sizeof(unsigned int), stream);

  dim3 grid(TILES_X, B);
  ga_fused_kernel<<<grid, BLOCK, 0, stream>>>(slen, tlen, p, partial, counter,
                                              out, B);
}

// Round 4
// 22.975 us; speedup vs baseline: 5.1802x; 5.1802x over previous
//
#include <hip/hip_runtime.h>
#include <hip/hip_bf16.h>

// GuidedAttentionLoss: out = sum(w * p over valid) / count(valid)
//   w = 1 - exp(-((s/il - t/ol)^2) / (2*sigma^2)), valid = (t<ol)&(s<il)
// Shapes fixed by reference: B=32, T=2048, S=512.
// Fused single kernel. Cross-block completion via RELAXED hierarchical
// counters (round 3 showed ACQ_REL agent RMWs cost ~43ns each serialized:
// 4096 of them = 175us). Ordering: sc-bypass atomic store + s_waitcnt
// vmcnt(0) before the counter RMW; RMW return value consumption orders the
// level-1 -> level-0 chain.

#define GA_T 2048
#define GA_S 512
#define GA_INV2S2 (1.0f / (2.0f * 0.4f * 0.4f))

#define BLOCK 256
#define ROWS_PER_BLOCK 32                 // rows of T per block
#define TILES_X (GA_T / ROWS_PER_BLOCK)   // 64
#define NPART (TILES_X * 32)              // 2048 blocks, 8/CU: one generation
#define NGRP 32                           // level-1 counters
#define GRP_ARRIVALS (NPART / NGRP)       // 64 arrivals per level-1 counter
#define CNT_STRIDE 16                     // uints; 64B between counters

__global__ __launch_bounds__(BLOCK) void ga_fused_kernel(
    const int* __restrict__ slen, const int* __restrict__ tlen,
    const float* __restrict__ p, float* __restrict__ partial,
    unsigned int* __restrict__ cnt1, unsigned int* __restrict__ cnt0,
    float* __restrict__ out, int B) {
  const int b = blockIdx.y;
  const int t0 = blockIdx.x * ROWS_PER_BLOCK;
  const int bi = b * gridDim.x + blockIdx.x;
  const int ol = tlen[b];

  float acc = 0.0f;

  if (t0 < ol) {
    const int il = slen[b];
    const float inv_il = 1.0f / (float)il;
    const float inv_ol = 1.0f / (float)ol;

    const int r = threadIdx.x >> 7;    // 0..1 (uniform per wave)
    const int sv = threadIdx.x & 127;  // column slot
    const int s0 = sv << 2;

    if (s0 < il) {
      const float ys0 = (float)(s0 + 0) * inv_il;
      const float ys1 = (float)(s0 + 1) * inv_il;
      const float ys2 = (float)(s0 + 2) * inv_il;
      const float ys3 = (float)(s0 + 3) * inv_il;
      const float m1 = (s0 + 1 < il) ? 1.0f : 0.0f;
      const float m2 = (s0 + 2 < il) ? 1.0f : 0.0f;
      const float m3 = (s0 + 3 < il) ? 1.0f : 0.0f;

      const float* base = p + ((size_t)(b * GA_T + t0 + r) * GA_S + s0);

#pragma unroll
      for (int rr = 0; rr < ROWS_PER_BLOCK; rr += 2) {
        const int t = t0 + rr + r;
        if (t >= ol) break;  // wave-uniform (r uniform per wave)
        const float4 pv = *reinterpret_cast<const float4*>(base + rr * GA_S);
        const float xo = (float)t * inv_ol;
        float d0 = ys0 - xo, d1 = ys1 - xo, d2 = ys2 - xo, d3 = ys3 - xo;
        float e0 = __expf(-(d0 * d0) * GA_INV2S2);
        float e1 = __expf(-(d1 * d1) * GA_INV2S2);
        float e2 = __expf(-(d2 * d2) * GA_INV2S2);
        float e3 = __expf(-(d3 * d3) * GA_INV2S2);
        float p0 = pv.x, p1 = m1 * pv.y, p2 = m2 * pv.z, p3 = m3 * pv.w;
        acc += p0 - p0 * e0;
        acc += p1 - p1 * e1;
        acc += p2 - p2 * e2;
        acc += p3 - p3 * e3;
      }
    }
  }

  // ---- block reduction (deterministic fixed tree) ----
  for (int off = 32; off > 0; off >>= 1)
    acc += __shfl_down(acc, off, 64);

  __shared__ float wsum[BLOCK / 64];
  __shared__ int sh_last;
  const int lane = threadIdx.x & 63;
  const int wid = threadIdx.x >> 6;
  if (lane == 0) wsum[wid] = acc;
  __syncthreads();

  if (threadIdx.x == 0) {
    float tot = (wsum[0] + wsum[1]) + (wsum[2] + wsum[3]);
    // sc-bypass store: visible at device coherence point once vmcnt retires
    __hip_atomic_store(&partial[bi], tot, __ATOMIC_RELAXED,
                       __HIP_MEMORY_SCOPE_AGENT);
    asm volatile("s_waitcnt vmcnt(0)" ::: "memory");  // store has completed
    const unsigned g = (unsigned)bi & (NGRP - 1);
    unsigned o1 = __hip_atomic_fetch_add(&cnt1[g * CNT_STRIDE], 1u,
                                         __ATOMIC_RELAXED,
                                         __HIP_MEMORY_SCOPE_AGENT);
    int is_last = 0;
    if (o1 == GRP_ARRIVALS - 1) {  // consuming o1 orders RMW1 -> RMW0
      unsigned o0 = __hip_atomic_fetch_add(cnt0, 1u, __ATOMIC_RELAXED,
                                           __HIP_MEMORY_SCOPE_AGENT);
      is_last = (o0 == NGRP - 1);
    }
    sh_last = is_last;
  }
  __syncthreads();
  if (!sh_last) return;

  // ---- last block: reduce all partials (deterministic fixed order) ----
  float v[NPART / BLOCK];  // 8
#pragma unroll
  for (int k = 0; k < NPART / BLOCK; ++k)
    v[k] = __hip_atomic_load(&partial[k * BLOCK + threadIdx.x],
                             __ATOMIC_RELAXED, __HIP_MEMORY_SCOPE_AGENT);
  double s = (((double)v[0] + (double)v[1]) + ((double)v[2] + (double)v[3])) +
             (((double)v[4] + (double)v[5]) + ((double)v[6] + (double)v[7]));

  __shared__ double sh[BLOCK];
  sh[threadIdx.x] = s;
  __syncthreads();
  for (int off = BLOCK / 2; off > 0; off >>= 1) {
    if (threadIdx.x < off) sh[threadIdx.x] += sh[threadIdx.x + off];
    __syncthreads();
  }
  if (threadIdx.x == 0) {
    double den = 0.0;
    for (int bb = 0; bb < B; ++bb)
      den += (double)slen[bb] * (double)tlen[bb];
    out[0] = (float)(sh[0] / den);
  }
}

extern "C" void kernel_launch(void* const* d_in, const int* in_sizes, int n_in,
                              void* d_out, int out_size, void* d_ws, size_t ws_size,
                              hipStream_t stream) {
  const int* slen = (const int*)d_in[0];
  const int* tlen = (const int*)d_in[1];
  const float* p = (const float*)d_in[2];
  float* out = (float*)d_out;

  // ws layout: [0, 8KB) partial floats; [8KB, 10KB) 32 counters @64B;
  //            [10KB, 10KB+64) top counter
  float* partial = (float*)d_ws;
  unsigned int* cnt1 = (unsigned int*)((char*)d_ws + NPART * sizeof(float));
  unsigned int* cnt0 = (unsigned int*)((char*)d_ws + NPART * sizeof(float) +
                                       NGRP * CNT_STRIDE * sizeof(unsigned int));

  const int B = in_sizes[0];  // 32

  // counters must be zero at kernel start every call (ws poisoned to 0xAA
  // before timing; kernel leaves them at their arrival totals)
  hipMemsetAsync(cnt1, 0, (NGRP * CNT_STRIDE + CNT_STRIDE) * sizeof(unsigned int),
                 stream);

  dim3 grid(TILES_X, 32);
  ga_fused_kernel<<<grid, BLOCK, 0, stream>>>(slen, tlen, p, partial, cnt1,
                                              cnt0, out, B);
}

// Round 5
// 16.049 us; speedup vs baseline: 7.4157x; 1.4315x over previous
//
#include <hip/hip_runtime.h>
#include <hip/hip_bf16.h>

// GuidedAttentionLoss: out = sum(w * p over valid) / count(valid)
//   w = 1 - exp(-((s/il - t/ol)^2) / (2*sigma^2)), valid = (t<ol)&(s<il)
// Shapes fixed by reference: B=32, T=2048, S=512.
// Two kernels (fusion via arrival counters measured SLOWER on this chip:
// r3 acq_rel = 180us, r4 relaxed hierarchical = ~17us kernel; plain
// two-kernel = 15.9us). This round slims both kernels instead.

#define GA_T 2048
#define GA_S 512
#define GA_INV2S2 (1.0f / (2.0f * 0.4f * 0.4f))

#define BLOCK 256
#define ROWS_PER_BLOCK 32                 // rows of T per block
#define TILES_X (GA_T / ROWS_PER_BLOCK)   // 64
#define NPART (TILES_X * 32)              // 2048 blocks = 8/CU, one generation

__global__ __launch_bounds__(BLOCK) void ga_partial_kernel(
    const int* __restrict__ slen, const int* __restrict__ tlen,
    const float* __restrict__ p, float* __restrict__ partial) {
  const int b = blockIdx.y;
  const int t0 = blockIdx.x * ROWS_PER_BLOCK;
  const int bi = b * gridDim.x + blockIdx.x;
  const int ol = tlen[b];

  float acc = 0.0f;

  if (t0 < ol) {
    const int il = slen[b];
    const float inv_il = 1.0f / (float)il;
    const float inv_ol = 1.0f / (float)ol;

    const int r = threadIdx.x >> 7;    // 0..1 (wave-uniform)
    const int sv = threadIdx.x & 127;  // column slot
    const int s0 = sv << 2;

    if (s0 < il) {
      const float ys0 = (float)(s0 + 0) * inv_il;
      const float ys1 = (float)(s0 + 1) * inv_il;
      const float ys2 = (float)(s0 + 2) * inv_il;
      const float ys3 = (float)(s0 + 3) * inv_il;
      const float m1 = (s0 + 1 < il) ? 1.0f : 0.0f;
      const float m2 = (s0 + 2 < il) ? 1.0f : 0.0f;
      const float m3 = (s0 + 3 < il) ? 1.0f : 0.0f;

      const float* base = p + ((size_t)(b * GA_T + t0 + r) * GA_S + s0);

#pragma unroll
      for (int rr = 0; rr < ROWS_PER_BLOCK; rr += 2) {
        const int t = t0 + rr + r;
        if (t >= ol) break;  // wave-uniform (r uniform per wave)
        const float4 pv = *reinterpret_cast<const float4*>(base + rr * GA_S);
        const float xo = (float)t * inv_ol;
        float d0 = ys0 - xo, d1 = ys1 - xo, d2 = ys2 - xo, d3 = ys3 - xo;
        float e0 = __expf(-(d0 * d0) * GA_INV2S2);
        float e1 = __expf(-(d1 * d1) * GA_INV2S2);
        float e2 = __expf(-(d2 * d2) * GA_INV2S2);
        float e3 = __expf(-(d3 * d3) * GA_INV2S2);
        // w*p = p - p*e (2 FMAs/elem), column-validity folded into p
        float p0 = pv.x, p1 = m1 * pv.y, p2 = m2 * pv.z, p3 = m3 * pv.w;
        acc += p0 - p0 * e0;
        acc += p1 - p1 * e1;
        acc += p2 - p2 * e2;
        acc += p3 - p3 * e3;
      }
    }
  }

  // ---- block reduction (deterministic fixed tree) ----
  for (int off = 32; off > 0; off >>= 1)
    acc += __shfl_down(acc, off, 64);

  __shared__ float wsum[BLOCK / 64];
  const int lane = threadIdx.x & 63;
  const int wid = threadIdx.x >> 6;
  if (lane == 0) wsum[wid] = acc;
  __syncthreads();

  if (threadIdx.x == 0) {
    // every block writes its partial every call (ws not re-poisoned, but we
    // fully overwrite all NPART slots)
    partial[bi] = (wsum[0] + wsum[1]) + (wsum[2] + wsum[3]);
  }
}

// Single-wave final: no LDS, no barriers. 64 threads read all NPART floats
// (8 coalesced float4 loads each), double-accumulate, shfl-tree reduce.
// den computed lane-parallel and reduced in the same chain.
__global__ __launch_bounds__(64) void ga_final_kernel(
    const int* __restrict__ slen, const int* __restrict__ tlen,
    const float* __restrict__ partial, int B, float* __restrict__ out) {
  const int lane = threadIdx.x;  // 0..63

  double s = 0.0;
#pragma unroll
  for (int k = 0; k < NPART / (64 * 4); ++k) {  // 8 iterations
    const float4 f =
        *reinterpret_cast<const float4*>(partial + (k * 64 + lane) * 4);
    s += ((double)f.x + (double)f.y) + ((double)f.z + (double)f.w);
  }

  double den = 0.0;
  if (lane < B) den = (double)slen[lane] * (double)tlen[lane];  // B == 32

#pragma unroll
  for (int off = 32; off > 0; off >>= 1) {
    s += __shfl_down(s, off, 64);
    den += __shfl_down(den, off, 64);
  }

  if (lane == 0) out[0] = (float)(s / den);
}

extern "C" void kernel_launch(void* const* d_in, const int* in_sizes, int n_in,
                              void* d_out, int out_size, void* d_ws, size_t ws_size,
                              hipStream_t stream) {
  const int* slen = (const int*)d_in[0];
  const int* tlen = (const int*)d_in[1];
  const float* p = (const float*)d_in[2];
  float* out = (float*)d_out;
  float* partial = (float*)d_ws;  // NPART floats = 8 KB

  const int B = in_sizes[0];  // 32

  dim3 grid(TILES_X, B);
  ga_partial_kernel<<<grid, BLOCK, 0, stream>>>(slen, tlen, p, partial);
  ga_final_kernel<<<1, 64, 0, stream>>>(slen, tlen, partial, B, out);
}

// Round 6
// 14.401 us; speedup vs baseline: 8.2644x; 1.1145x over previous
//
#include <hip/hip_runtime.h>
#include <hip/hip_bf16.h>

// GuidedAttentionLoss: out = sum(w * p over valid) / count(valid)
//   w = 1 - exp(-((s/il - t/ol)^2) / (2*sigma^2)), valid = (t<ol)&(s<il)
// Shapes fixed by reference: B=32, T=2048, S=512.
//
// R5 post-mortem: grid (tile, batch) mapping pinned each CU to a FIXED row
// tile -> systematic 2x+ load imbalance (tail CU ~10us). This round: global
// valid-slot space, equal contiguous chunk per block -> near-perfect balance.

#define GA_T 2048
#define GA_S 512
#define GA_INV2S2 (1.0f / (2.0f * 0.4f * 0.4f))

#define BLOCK 256
#define NBLK 2048   // 8 blocks/CU, one resident generation
#define GA_B 32

__global__ __launch_bounds__(BLOCK) void ga_partial_kernel(
    const int* __restrict__ slen, const int* __restrict__ tlen,
    const float* __restrict__ p, float* __restrict__ partial) {
  // per-batch tables in LDS
  __shared__ unsigned pref[GA_B + 1];   // slot prefix sum
  __shared__ unsigned Wsh[GA_B];        // slots per valid row = ceil(il/4)
  __shared__ int ilsh[GA_B];
  __shared__ float inv_il_sh[GA_B], inv_ol_sh[GA_B];
  __shared__ unsigned szsh[GA_B];

  if (threadIdx.x < GA_B) {
    const int b = threadIdx.x;
    const int il = slen[b];
    const int ol = tlen[b];
    const unsigned W = (unsigned)((il + 3) >> 2);
    Wsh[b] = W;
    ilsh[b] = il;
    inv_il_sh[b] = 1.0f / (float)il;
    inv_ol_sh[b] = 1.0f / (float)ol;
    szsh[b] = W * (unsigned)ol;
  }
  __syncthreads();
  if (threadIdx.x == 0) {
    unsigned run = 0;
#pragma unroll
    for (int b = 0; b < GA_B; ++b) { pref[b] = run; run += szsh[b]; }
    pref[GA_B] = run;
  }
  __syncthreads();

  const unsigned S_tot = pref[GA_B];
  const unsigned chunk = (S_tot + NBLK - 1) / NBLK;
  const unsigned start = blockIdx.x * chunk;
  const unsigned end = (start + chunk < S_tot) ? (start + chunk) : S_tot;

  float acc = 0.0f;

  for (unsigned q = start + threadIdx.x; q < end; q += BLOCK) {
    // largest b with pref[b] <= q  (5-step binary search; 0..31)
    int b = 0;
#pragma unroll
    for (int step = 16; step > 0; step >>= 1)
      if (pref[b + step] <= q) b += step;

    const unsigned qr = q - pref[b];
    const unsigned W = Wsh[b];
    const unsigned t = qr / W;           // valid row (t < ol guaranteed)
    const unsigned sv = qr - t * W;      // slot in row (s0 < il guaranteed)
    const int s0 = (int)(sv << 2);
    const int il = ilsh[b];
    const float inv_il = inv_il_sh[b];
    const float xo = (float)t * inv_ol_sh[b];

    const float4 pv = *reinterpret_cast<const float4*>(
        p + ((size_t)(b * GA_T + (int)t) * GA_S + s0));

    const float d0 = (float)(s0 + 0) * inv_il - xo;
    const float d1 = (float)(s0 + 1) * inv_il - xo;
    const float d2 = (float)(s0 + 2) * inv_il - xo;
    const float d3 = (float)(s0 + 3) * inv_il - xo;
    const float e0 = __expf(-(d0 * d0) * GA_INV2S2);
    const float e1 = __expf(-(d1 * d1) * GA_INV2S2);
    const float e2 = __expf(-(d2 * d2) * GA_INV2S2);
    const float e3 = __expf(-(d3 * d3) * GA_INV2S2);
    // w*p = p - p*e; fold column-validity masks into p
    const float p0 = pv.x;
    const float p1 = (s0 + 1 < il) ? pv.y : 0.0f;
    const float p2 = (s0 + 2 < il) ? pv.z : 0.0f;
    const float p3 = (s0 + 3 < il) ? pv.w : 0.0f;
    acc += p0 - p0 * e0;
    acc += p1 - p1 * e1;
    acc += p2 - p2 * e2;
    acc += p3 - p3 * e3;
  }

  // ---- block reduction (deterministic fixed tree) ----
  for (int off = 32; off > 0; off >>= 1)
    acc += __shfl_down(acc, off, 64);

  __shared__ float wsum[BLOCK / 64];
  const int lane = threadIdx.x & 63;
  const int wid = threadIdx.x >> 6;
  if (lane == 0) wsum[wid] = acc;
  __syncthreads();

  if (threadIdx.x == 0)
    partial[blockIdx.x] = (wsum[0] + wsum[1]) + (wsum[2] + wsum[3]);
}

// Single-wave final: no LDS, no barriers. 64 threads read all NBLK floats
// (8 coalesced float4 loads each), double-accumulate, shfl-tree reduce.
// den = sum(slen*tlen) computed lane-parallel in the same chain.
__global__ __launch_bounds__(64) void ga_final_kernel(
    const int* __restrict__ slen, const int* __restrict__ tlen,
    const float* __restrict__ partial, int B, float* __restrict__ out) {
  const int lane = threadIdx.x;  // 0..63

  double s = 0.0;
#pragma unroll
  for (int k = 0; k < NBLK / (64 * 4); ++k) {  // 8 iterations
    const float4 f =
        *reinterpret_cast<const float4*>(partial + (k * 64 + lane) * 4);
    s += ((double)f.x + (double)f.y) + ((double)f.z + (double)f.w);
  }

  double den = 0.0;
  if (lane < B) den = (double)slen[lane] * (double)tlen[lane];  // B == 32

#pragma unroll
  for (int off = 32; off > 0; off >>= 1) {
    s += __shfl_down(s, off, 64);
    den += __shfl_down(den, off, 64);
  }

  if (lane == 0) out[0] = (float)(s / den);
}

extern "C" void kernel_launch(void* const* d_in, const int* in_sizes, int n_in,
                              void* d_out, int out_size, void* d_ws, size_t ws_size,
                              hipStream_t stream) {
  const int* slen = (const int*)d_in[0];
  const int* tlen = (const int*)d_in[1];
  const float* p = (const float*)d_in[2];
  float* out = (float*)d_out;
  float* partial = (float*)d_ws;  // NBLK floats = 8 KB

  const int B = in_sizes[0];  // 32

  ga_partial_kernel<<<NBLK, BLOCK, 0, stream>>>(slen, tlen, p, partial);
  ga_final_kernel<<<1, 64, 0, stream>>>(slen, tlen, partial, B, out);
}

// Round 7
// 13.638 us; speedup vs baseline: 8.7268x; 1.0559x over previous
//
#include <hip/hip_runtime.h>
#include <hip/hip_bf16.h>

// GuidedAttentionLoss: out = sum(w * p over valid) / count(valid)
//   w = 1 - exp(-((s/il - t/ol)^2) / (2*sigma^2)), valid = (t<ol)&(s<il)
// Shapes fixed by reference: B=32, T=2048, S=512.
//
// R6: balanced slot-space mapping (r6, 14.4us). This round: 4-deep load
// pipelining inside the q-loop (mapping chain previously serialized the
// ~900cy HBM loads per wave), wave-scan setup, nontemporal streaming loads.

#define GA_T 2048
#define GA_S 512
#define GA_INV2S2 (1.0f / (2.0f * 0.4f * 0.4f))

#define BLOCK 256
#define NBLK 2048   // 8 blocks/CU, one resident generation
#define GA_B 32

typedef float f32x4 __attribute__((ext_vector_type(4)));

__global__ __launch_bounds__(BLOCK) void ga_partial_kernel(
    const int* __restrict__ slen, const int* __restrict__ tlen,
    const float* __restrict__ p, float* __restrict__ partial) {
  __shared__ unsigned pref[GA_B + 1];   // slot prefix sum, pref[0]=0
  __shared__ unsigned Wsh[GA_B];        // slots per valid row = ceil(il/4)
  __shared__ int ilsh[GA_B];
  __shared__ float inv_il_sh[GA_B], inv_ol_sh[GA_B];

  const int tid = threadIdx.x;

  // ---- setup: first wave builds tables + shfl-scan prefix (no serial loop)
  if (tid < 64) {
    unsigned sz = 0;
    if (tid < GA_B) {
      const int il = slen[tid];
      const int ol = tlen[tid];
      const unsigned W = (unsigned)((il + 3) >> 2);
      Wsh[tid] = W;
      ilsh[tid] = il;
      inv_il_sh[tid] = 1.0f / (float)il;
      inv_ol_sh[tid] = 1.0f / (float)ol;
      sz = W * (unsigned)ol;
    }
    unsigned v = sz;  // inclusive scan over lanes 0..31 (5 steps)
#pragma unroll
    for (int d = 1; d < 32; d <<= 1) {
      unsigned u = __shfl_up(v, d, 64);
      v += (tid >= d) ? u : 0u;
    }
    if (tid < GA_B) pref[tid + 1] = v;
    if (tid == 0) pref[0] = 0;
  }
  __syncthreads();

  const unsigned S_tot = pref[GA_B];
  const unsigned chunk = (S_tot + NBLK - 1) / NBLK;
  const unsigned start = (unsigned)blockIdx.x * chunk;
  const unsigned end = (start + chunk < S_tot) ? (start + chunk) : S_tot;
  const unsigned ITERS = (chunk + BLOCK - 1) / BLOCK;  // grid-uniform

  float acc = 0.0f;

  for (unsigned it0 = 0; it0 < ITERS; it0 += 4) {
    // ---- stage A: map 4 slots, issue 4 independent loads ----
    f32x4 pv[4];
    float xo[4], invil[4], ok[4], m1[4], m2[4], m3[4];
    int s0v[4];
#pragma unroll
    for (int j = 0; j < 4; ++j) {
      const unsigned it = it0 + (unsigned)j;
      const unsigned q = start + it * BLOCK + (unsigned)tid;
      const bool valid = (it < ITERS) && (q < end);
      ok[j] = valid ? 1.0f : 0.0f;
      const unsigned qc = valid ? q : (S_tot - 1);  // in-bounds clamp
      int b = 0;  // largest b with pref[b] <= qc (5-step search, LDS bcast)
#pragma unroll
      for (int step = 16; step > 0; step >>= 1)
        if (pref[b + step] <= qc) b += step;
      const unsigned qr = qc - pref[b];
      const unsigned W = Wsh[b];
      const unsigned t = qr / W;       // valid row (t < ol guaranteed)
      const unsigned sv = qr - t * W;  // row slot (s0 < il guaranteed)
      const int s0 = (int)(sv << 2);
      const int il = ilsh[b];
      s0v[j] = s0;
      invil[j] = inv_il_sh[b];
      xo[j] = (float)t * inv_ol_sh[b];
      m1[j] = (s0 + 1 < il) ? 1.0f : 0.0f;
      m2[j] = (s0 + 2 < il) ? 1.0f : 0.0f;
      m3[j] = (s0 + 3 < il) ? 1.0f : 0.0f;
      pv[j] = __builtin_nontemporal_load(reinterpret_cast<const f32x4*>(
          p + ((size_t)(b * GA_T + (int)t) * GA_S + s0)));
    }
    // ---- stage B: compute on all 4 ----
#pragma unroll
    for (int j = 0; j < 4; ++j) {
      const float d0 = (float)(s0v[j] + 0) * invil[j] - xo[j];
      const float d1 = (float)(s0v[j] + 1) * invil[j] - xo[j];
      const float d2 = (float)(s0v[j] + 2) * invil[j] - xo[j];
      const float d3 = (float)(s0v[j] + 3) * invil[j] - xo[j];
      const float e0 = __expf(-(d0 * d0) * GA_INV2S2);
      const float e1 = __expf(-(d1 * d1) * GA_INV2S2);
      const float e2 = __expf(-(d2 * d2) * GA_INV2S2);
      const float e3 = __expf(-(d3 * d3) * GA_INV2S2);
      // w*p = p - p*e; fold validity + column masks into p
      const float p0 = ok[j] * pv[j][0];
      const float p1 = ok[j] * m1[j] * pv[j][1];
      const float p2 = ok[j] * m2[j] * pv[j][2];
      const float p3 = ok[j] * m3[j] * pv[j][3];
      acc += p0 - p0 * e0;
      acc += p1 - p1 * e1;
      acc += p2 - p2 * e2;
      acc += p3 - p3 * e3;
    }
  }

  // ---- block reduction (deterministic fixed tree) ----
  for (int off = 32; off > 0; off >>= 1)
    acc += __shfl_down(acc, off, 64);

  __shared__ float wsum[BLOCK / 64];
  const int lane = threadIdx.x & 63;
  const int wid = threadIdx.x >> 6;
  if (lane == 0) wsum[wid] = acc;
  __syncthreads();

  if (threadIdx.x == 0)
    partial[blockIdx.x] = (wsum[0] + wsum[1]) + (wsum[2] + wsum[3]);
}

// Single-wave final: no LDS, no barriers. 64 threads read all NBLK floats
// (8 independent coalesced float4 loads each), double-accumulate,
// shfl-tree reduce. den computed lane-parallel in the same chain.
__global__ __launch_bounds__(64) void ga_final_kernel(
    const int* __restrict__ slen, const int* __restrict__ tlen,
    const float* __restrict__ partial, int B, float* __restrict__ out) {
  const int lane = threadIdx.x;  // 0..63

  f32x4 f[NBLK / (64 * 4)];  // 8 independent loads
#pragma unroll
  for (int k = 0; k < NBLK / (64 * 4); ++k)
    f[k] = *reinterpret_cast<const f32x4*>(partial + (k * 64 + lane) * 4);

  double s = 0.0;
#pragma unroll
  for (int k = 0; k < NBLK / (64 * 4); ++k)
    s += ((double)f[k][0] + (double)f[k][1]) +
         ((double)f[k][2] + (double)f[k][3]);

  double den = 0.0;
  if (lane < B) den = (double)slen[lane] * (double)tlen[lane];  // B == 32

#pragma unroll
  for (int off = 32; off > 0; off >>= 1) {
    s += __shfl_down(s, off, 64);
    den += __shfl_down(den, off, 64);
  }

  if (lane == 0) out[0] = (float)(s / den);
}

extern "C" void kernel_launch(void* const* d_in, const int* in_sizes, int n_in,
                              void* d_out, int out_size, void* d_ws, size_t ws_size,
                              hipStream_t stream) {
  const int* slen = (const int*)d_in[0];
  const int* tlen = (const int*)d_in[1];
  const float* p = (const float*)d_in[2];
  float* out = (float*)d_out;
  float* partial = (float*)d_ws;  // NBLK floats = 8 KB

  const int B = in_sizes[0];  // 32

  ga_partial_kernel<<<NBLK, BLOCK, 0, stream>>>(slen, tlen, p, partial);
  ga_final_kernel<<<1, 64, 0, stream>>>(slen, tlen, partial, B, out);
}